// Round 3
// baseline (6252.255 us; speedup 1.0000x reference)
//
#include <hip/hip_runtime.h>

// Problem constants
#define Hh    100
#define Ww    152
#define Pp    15200        // H*W
#define Cc    256
#define NBATCH 8
#define NC1   81
#define NCLS  80
#define KTOP  100

// conv tile: 256 flat pixels x 128 out-channels per block
#define BN 256
#define BM 128

// B-tile LDS swizzle (float4 granularity): spreads stride-2-float4 lane
// addresses from 4 bank-groups (4-way) to 8 groups (2-way = free on wave64).
__device__ __forceinline__ int swz(int L) { return L ^ ((L >> 3) & 1); }

// ---------------------------------------------------------------------------
// Kernel 0: one-time transpose w1 [k][c*9+t] -> w1t [c*9+t][k] so conv A-tile
// staging has coalesced global loads AND conflict-free LDS stores.
// ---------------------------------------------------------------------------
__global__ void transpose_w1(const float* __restrict__ w1, float* __restrict__ w1t)
{
    int ct = blockIdx.x;        // 0..2303
    int k  = threadIdx.x;       // 0..255
    w1t[ct * 256 + k] = w1[k * 2304 + ct];
}

// ---------------------------------------------------------------------------
// Kernel 1: 3x3 conv (SAME, stride 1) + bias + ReLU.
// Implicit GEMM, 256 px x 128 k per block, BK=8 channels. Thread tile:
// 16 k x 8 px (acc[16][8]); tx=tid&31 (px group), ty=tid>>5 (k group).
// B rows stored per-(channel,row) as [4 zero | 152 data | 4 zero] so SAME
// padding comes from LDS zeros: since 152%8==0, 8-px groups never cross a
// row, and b = window[3+j+dx] needs NO border cndmask at all.
// ---------------------------------------------------------------------------
__global__ __launch_bounds__(256, 2)
void conv3x3_relu(const float* __restrict__ x, const float* __restrict__ w1t,
                  const float* __restrict__ b1, float* __restrict__ hid)
{
    __shared__ float As[72 * 128];   // [ct = cl*9+tap][k]   36.9 KB
    __shared__ float Bs[6400];       // 8 cl x 5 rows x 40 float4, swizzled. 25.6 KB

    const int tid = threadIdx.x;
    const int p0  = blockIdx.x * BN;
    const int k0  = blockIdx.y * BM;
    const int n   = blockIdx.z;
    const int y0  = p0 / Ww;
    const int tx  = tid & 31;            // pixel group (8 px each)
    const int ty  = tid >> 5;            // out-channel group (16 k each)
    const int s   = p0 + tx * 8;         // first flat pixel of this thread
    const int ys  = s / Ww;              // its row (group never crosses rows)
    const int xs  = s - ys * Ww;         // column of first pixel (mult of 8)
    const int ryt = ys - y0 + 1;         // local row slot for dy=0 (1..3)
    const int baseoff = (ryt - 1) * 40 + (xs >> 2);  // window chunk offset, dy=0

    float acc[16][8];
#pragma unroll
    for (int a = 0; a < 16; ++a)
#pragma unroll
        for (int b = 0; b < 8; ++b) acc[a][b] = 0.f;

    const size_t xbase = (size_t)n * Cc * Pp;

#pragma unroll 1
    for (int c0 = 0; c0 < Cc; c0 += 8) {
        // ---- stage A from w1t: 72 rows (local ct) x 128 k = 2304 float4 ----
#pragma unroll
        for (int i = 0; i < 9; ++i) {
            int q   = i * 256 + tid;     // float4 id
            int row = q >> 5;            // 32 float4 per row
            int c4  = q & 31;
            float4 v = *(const float4*)(w1t + ((size_t)(c0 * 9 + row) * 256) + k0 + c4 * 4);
            *(float4*)(&As[row * 128 + c4 * 4]) = v;
        }
        // ---- stage B: 8 cl x 5 rows (y0-1..y0+3) x 40 chunks = 1600 float4 ----
#pragma unroll
        for (int i = 0; i < 7; ++i) {
            int q = i * 256 + tid;       // == logical chunk L
            if (q < 1600) {
                int cl  = q / 200;
                int rem = q - cl * 200;
                int ry  = rem / 40;
                int f   = rem - ry * 40; // chunk within row; 0 and 39 are pads
                int y   = y0 - 1 + ry;
                float4 v = make_float4(0.f, 0.f, 0.f, 0.f);
                if (f >= 1 && f <= 38 && (unsigned)y < (unsigned)Hh)
                    v = *(const float4*)(x + xbase + (size_t)(c0 + cl) * Pp + y * Ww + (f - 1) * 4);
                *(float4*)(&Bs[swz(q) * 4]) = v;
            }
        }
        __syncthreads();

        // ---- compute ----
#pragma unroll 1
        for (int cl = 0; cl < 8; ++cl) {
#pragma unroll
            for (int dy = 0; dy < 3; ++dy) {
                int L = cl * 200 + dy * 40 + baseoff;   // window: columns xs-4..xs+11
                float4 q0 = *(const float4*)(&Bs[swz(L    ) * 4]);
                float4 q1 = *(const float4*)(&Bs[swz(L + 1) * 4]);
                float4 q2 = *(const float4*)(&Bs[swz(L + 2) * 4]);
                float4 q3 = *(const float4*)(&Bs[swz(L + 3) * 4]);
                float r[16] = {q0.x,q0.y,q0.z,q0.w, q1.x,q1.y,q1.z,q1.w,
                               q2.x,q2.y,q2.z,q2.w, q3.x,q3.y,q3.z,q3.w};
                const float* ap = &As[(cl * 9 + dy * 3) * 128 + ty * 16];
#pragma unroll
                for (int dx = 0; dx < 3; ++dx) {
                    float4 a0 = *(const float4*)(ap + dx * 128);
                    float4 a1 = *(const float4*)(ap + dx * 128 + 4);
                    float4 a2 = *(const float4*)(ap + dx * 128 + 8);
                    float4 a3 = *(const float4*)(ap + dx * 128 + 12);
                    float a[16] = {a0.x,a0.y,a0.z,a0.w, a1.x,a1.y,a1.z,a1.w,
                                   a2.x,a2.y,a2.z,a2.w, a3.x,a3.y,a3.z,a3.w};
#pragma unroll
                    for (int ko = 0; ko < 16; ++ko)
#pragma unroll
                        for (int j = 0; j < 8; ++j)
                            acc[ko][j] = fmaf(a[ko], r[3 + j + dx], acc[ko][j]);
                }
            }
        }
        __syncthreads();
    }

    // ---- epilogue: bias + relu, float4 stores ----
    if (s < Pp) {
#pragma unroll
        for (int ko = 0; ko < 16; ++ko) {
            int k = k0 + ty * 16 + ko;
            float bias = b1[k];
            float4 v0, v1;
            v0.x = fmaxf(acc[ko][0] + bias, 0.f);
            v0.y = fmaxf(acc[ko][1] + bias, 0.f);
            v0.z = fmaxf(acc[ko][2] + bias, 0.f);
            v0.w = fmaxf(acc[ko][3] + bias, 0.f);
            v1.x = fmaxf(acc[ko][4] + bias, 0.f);
            v1.y = fmaxf(acc[ko][5] + bias, 0.f);
            v1.z = fmaxf(acc[ko][6] + bias, 0.f);
            v1.w = fmaxf(acc[ko][7] + bias, 0.f);
            float* dst = hid + ((size_t)n * Cc + k) * Pp + s;
            *(float4*)dst = v0;
            *(float4*)(dst + 4) = v1;
        }
    }
}

// ---------------------------------------------------------------------------
// Kernel 2: 1x1 conv to 81 logits + bias, softmax over 81, argmax over 80.
// Writes logits (output 2) and per-pixel (p = prob of argmax class, c) maps.
// ---------------------------------------------------------------------------
__global__ __launch_bounds__(256, 2)
void conv1x1_softmax(const float* __restrict__ hid, const float* __restrict__ w2,
                     const float* __restrict__ b2, float* __restrict__ logits,
                     float* __restrict__ pmap, int* __restrict__ cmap)
{
    __shared__ float w2s[64 * 84];   // [c_l][j], j padded 81->84 with zeros
    const int tid = threadIdx.x;
    const int p   = blockIdx.x * 256 + tid;
    const int n   = blockIdx.y;
    const bool valid = (p < Pp);
    const int psafe = valid ? p : 0;

    float acc[84];
#pragma unroll
    for (int j = 0; j < 84; ++j) acc[j] = 0.f;

#pragma unroll 1
    for (int c0 = 0; c0 < Cc; c0 += 64) {
        __syncthreads();
#pragma unroll
        for (int i = 0; i < 21; ++i) {   // 21*256 == 64*84
            int q  = i * 256 + tid;
            int cl = q / 84;
            int j  = q - cl * 84;
            float v = 0.f;
            if (j < NC1) v = w2[j * 256 + c0 + cl];
            w2s[cl * 84 + j] = v;
        }
        __syncthreads();

        const float* hptr = hid + ((size_t)n * Cc + c0) * Pp + psafe;
#pragma unroll 2
        for (int cl = 0; cl < 64; ++cl) {
            float h = hptr[(size_t)cl * Pp];
            const float4* wrow = (const float4*)(&w2s[cl * 84]);
#pragma unroll
            for (int f = 0; f < 21; ++f) {
                float4 wv = wrow[f];
                acc[f * 4 + 0] = fmaf(wv.x, h, acc[f * 4 + 0]);
                acc[f * 4 + 1] = fmaf(wv.y, h, acc[f * 4 + 1]);
                acc[f * 4 + 2] = fmaf(wv.z, h, acc[f * 4 + 2]);
                acc[f * 4 + 3] = fmaf(wv.w, h, acc[f * 4 + 3]);
            }
        }
    }

    if (valid) {
#pragma unroll
        for (int j = 0; j < NC1; ++j) acc[j] += b2[j];

        float* lp = logits + (size_t)n * NC1 * Pp + p;
#pragma unroll
        for (int j = 0; j < NC1; ++j) lp[(size_t)j * Pp] = acc[j];

        float m = -3.4e38f;
#pragma unroll
        for (int j = 0; j < NC1; ++j) m = fmaxf(m, acc[j]);
        float s = 0.f;
#pragma unroll
        for (int j = 0; j < NC1; ++j) s += __expf(acc[j] - m);
        float best = -3.4e38f; int bi = 0;
#pragma unroll
        for (int j = 0; j < NCLS; ++j) {   // first occurrence wins (strict >)
            if (acc[j] > best) { best = acc[j]; bi = j; }
        }
        pmap[n * Pp + p] = __expf(best - m) / s;
        cmap[n * Pp + p] = bi;
    }
}

// ---------------------------------------------------------------------------
// Kernel 3: score = p + 1{local max}. Only the argmax channel is nonzero at
// each pixel, so 81-ch local-max reduces to: no 8-neighbor with same class
// and strictly larger p (and p >= eps).
// ---------------------------------------------------------------------------
__global__ void local_score(const float* __restrict__ pmap, const int* __restrict__ cmap,
                            float* __restrict__ scores)
{
    int p = blockIdx.x * 256 + threadIdx.x;
    int n = blockIdx.y;
    if (p >= Pp) return;
    int base = n * Pp;
    float pv = pmap[base + p];
    int   c  = cmap[base + p];
    int y = p / Ww, xc = p - y * Ww;
    bool ok = (pv >= 1e-6f);
#pragma unroll
    for (int dy = -1; dy <= 1; ++dy)
#pragma unroll
        for (int dx = -1; dx <= 1; ++dx) {
            if (dy == 0 && dx == 0) continue;
            int yy = y + dy, xx = xc + dx;
            if (yy >= 0 && yy < Hh && xx >= 0 && xx < Ww) {
                int q = base + yy * Ww + xx;
                if (cmap[q] == c && pmap[q] > pv) ok = false;
            }
        }
    scores[base + p] = pv + (ok ? 1.f : 0.f);
}

// ---------------------------------------------------------------------------
// Kernel 4: per-batch top-100 (lax.top_k semantics: value desc, index asc on
// ties) via 100 iterations of block-wide max over LDS-resident scores, using
// composite key (float_bits << 32) | (0xFFFF - idx). Then gathers x / pos.
// ---------------------------------------------------------------------------
__global__ __launch_bounds__(256)
void topk_gather(const float* __restrict__ scores, const float* __restrict__ x,
                 const float* __restrict__ pos, float* __restrict__ oprop,
                 float* __restrict__ opos)
{
    __shared__ float sv[Pp];                 // 60.8 KB
    __shared__ int sidx[KTOP];
    __shared__ unsigned long long red[4];
    const int tid = threadIdx.x;
    const int n   = blockIdx.x;

    for (int i = tid; i < Pp; i += 256) sv[i] = scores[n * Pp + i];
    __syncthreads();

    for (int it = 0; it < KTOP; ++it) {
        unsigned long long best = 0ull;
        for (int i = tid; i < Pp; i += 256) {
            unsigned fb = __float_as_uint(sv[i]);   // scores > 0 => monotone bits
            unsigned long long key =
                ((unsigned long long)fb << 32) | (unsigned)(0xFFFF - i);
            best = key > best ? key : best;
        }
#pragma unroll
        for (int off = 32; off > 0; off >>= 1) {
            unsigned long long o = __shfl_down(best, off, 64);
            best = o > best ? o : best;
        }
        if ((tid & 63) == 0) red[tid >> 6] = best;
        __syncthreads();
        if (tid == 0) {
            unsigned long long b = red[0];
            b = red[1] > b ? red[1] : b;
            b = red[2] > b ? red[2] : b;
            b = red[3] > b ? red[3] : b;
            int idx = 0xFFFF - (int)(b & 0xFFFFFFFFull);
            sidx[it] = idx;
            sv[idx]  = 0.f;                  // remove winner
        }
        __syncthreads();
    }

    for (int t = tid; t < Cc * KTOP; t += 256) {
        int c = t / KTOP;
        int i = t - c * KTOP;
        int idx = sidx[i];
        oprop[n * Cc * KTOP + c * KTOP + i] = x[((size_t)n * Cc + c) * Pp + idx];
        opos [n * Cc * KTOP + c * KTOP + i] = pos[(size_t)c * Pp + idx];
    }
}

// ---------------------------------------------------------------------------
extern "C" void kernel_launch(void* const* d_in, const int* in_sizes, int n_in,
                              void* d_out, int out_size, void* d_ws, size_t ws_size,
                              hipStream_t stream)
{
    const float* x   = (const float*)d_in[0];
    const float* pos = (const float*)d_in[1];
    const float* w1  = (const float*)d_in[2];
    const float* b1  = (const float*)d_in[3];
    const float* w2  = (const float*)d_in[4];
    const float* b2  = (const float*)d_in[5];

    float* out    = (float*)d_out;
    float* oprop  = out;                                         // (8,256,100)
    float* oposE  = out + (size_t)NBATCH * Cc * KTOP;            // (8,256,100)
    float* logits = out + (size_t)2 * NBATCH * Cc * KTOP;        // (8,81,100,152)

    // w1t (2304x256 floats = 2.36 MB) borrows the logits region of d_out:
    // written before conv3x3, consumed by conv3x3, overwritten by conv1x1.
    float* w1t = logits;

    // workspace layout (floats): hid | pmap | cmap | scores
    float* ws     = (float*)d_ws;
    float* hid    = ws;                                          // 8*256*15200
    float* pmap   = ws + (size_t)NBATCH * Cc * Pp;               // 8*15200
    int*   cmap   = (int*)(pmap + (size_t)NBATCH * Pp);          // 8*15200
    float* scores = (float*)(cmap + (size_t)NBATCH * Pp);        // 8*15200

    transpose_w1<<<2304, 256, 0, stream>>>(w1, w1t);
    conv3x3_relu<<<dim3((Pp + BN - 1) / BN, Cc / BM, NBATCH), 256, 0, stream>>>(
        x, w1t, b1, hid);
    conv1x1_softmax<<<dim3((Pp + 255) / 256, NBATCH), 256, 0, stream>>>(
        hid, w2, b2, logits, pmap, cmap);
    local_score<<<dim3((Pp + 255) / 256, NBATCH), 256, 0, stream>>>(
        pmap, cmap, scores);
    topk_gather<<<NBATCH, 256, 0, stream>>>(scores, x, pos, oprop, oposE);
}

// Round 4
// 2605.711 us; speedup vs baseline: 2.3994x; 2.3994x over previous
//
#include <hip/hip_runtime.h>

// Problem constants
#define Hh    100
#define Ww    152
#define Pp    15200        // H*W
#define Cc    256
#define NBATCH 8
#define NC1   81
#define NCLS  80
#define KTOP  100

// conv tile: 128 flat pixels x 128 out-channels per block
#define BN 128
#define BM 128

// B-tile LDS swizzle (float4 granularity): spreads stride-2-float4 lane
// addresses from 4 bank-quads (4-way) to 8 quads (2-way = free on wave64).
__device__ __forceinline__ int swz(int L) { return L ^ ((L >> 3) & 1); }

// ---------------------------------------------------------------------------
// Kernel 0: one-time transpose w1 [k][c*9+t] -> w1t [c*9+t][k] so conv A
// reads are k-contiguous 32-B segments.
// ---------------------------------------------------------------------------
__global__ void transpose_w1(const float* __restrict__ w1, float* __restrict__ w1t)
{
    int ct = blockIdx.x;        // 0..2303
    int k  = threadIdx.x;       // 0..255
    w1t[ct * 256 + k] = w1[k * 2304 + ct];
}

// ---------------------------------------------------------------------------
// Kernel 1: 3x3 conv (SAME) + bias + ReLU. Implicit GEMM, 128 px x 128 k per
// block, BK=8, acc[8][8] (spill-safe). A (weights) read straight from global
// (L1/L2-resident w1t) on the VMEM pipe; LDS holds only the double-buffered
// B tile: 8 ch x 4 rows x [4 zeros|152|4 zeros] so SAME padding comes from
// LDS zeros (152%8==0 => 8-px thread groups never straddle a row) — zero
// border cndmasks. One barrier per K-iter; prefetch overlaps compute.
// ---------------------------------------------------------------------------
__global__ __launch_bounds__(256, 3)
void conv3x3_relu(const float* __restrict__ x, const float* __restrict__ w1t,
                  const float* __restrict__ b1, float* __restrict__ hid)
{
    __shared__ float Bs[2][5120];        // 2 x (8 cl x 4 rows x 40 float4) = 41 KB

    const int tid = threadIdx.x;
    const int p0  = blockIdx.x * BN;
    const int k0  = blockIdx.y * BM;
    const int n   = blockIdx.z;
    const int y0  = p0 / Ww;
    const int tx  = tid & 15;            // pixel group (8 px)
    const int ty  = tid >> 4;            // out-channel group (8 k)
    const int s   = p0 + tx * 8;         // first flat pixel (8-aligned => no row straddle)
    const int ys  = s / Ww;
    const int xs  = s - ys * Ww;         // multiple of 8
    const int rbase = (ys - y0) * 40 + (xs >> 2);  // window chunk offset at dy=0

    // staging precompute: 5 float4 chunks per thread, q = i*256+tid
    int  soff[5]; bool sval[5]; int sdst[5];
#pragma unroll
    for (int i = 0; i < 5; ++i) {
        int q  = i * 256 + tid;          // logical chunk 0..1279
        int cl = q / 160, rem = q - cl * 160;
        int ry = rem / 40, f = rem - ry * 40;   // f: 0,39 = pad chunks
        int y  = y0 - 1 + ry;
        bool v = (f >= 1) && (f <= 38) && ((unsigned)y < (unsigned)Hh);
        soff[i] = cl * Pp + (v ? y * Ww + (f - 1) * 4 : 0);
        sval[i] = v;
        sdst[i] = swz(q) * 4;
    }

    const float* xb = x + (size_t)n * Cc * Pp;

    float acc[8][8];
#pragma unroll
    for (int a = 0; a < 8; ++a)
#pragma unroll
        for (int b = 0; b < 8; ++b) acc[a][b] = 0.f;

    // prologue: stage c0=0 into buf 0
#pragma unroll
    for (int i = 0; i < 5; ++i) {
        float4 v = make_float4(0.f, 0.f, 0.f, 0.f);
        if (sval[i]) v = *(const float4*)(xb + soff[i]);
        *(float4*)(&Bs[0][sdst[i]]) = v;
    }
    __syncthreads();

#pragma unroll 1
    for (int c0 = 0; c0 < Cc; c0 += 8) {
        const int cur = (c0 >> 3) & 1;
        // prefetch next chunk into the other buffer (overlaps compute below;
        // safe: other buf's readers finished before previous barrier)
        if (c0 + 8 < Cc) {
            const float* xc = xb + (size_t)(c0 + 8) * Pp;
#pragma unroll
            for (int i = 0; i < 5; ++i) {
                float4 v = make_float4(0.f, 0.f, 0.f, 0.f);
                if (sval[i]) v = *(const float4*)(xc + soff[i]);
                *(float4*)(&Bs[cur ^ 1][sdst[i]]) = v;
            }
        }

        const float* BsC = Bs[cur];
#pragma unroll 1
        for (int cl = 0; cl < 8; ++cl) {
            const float* wp = w1t + ((size_t)((c0 + cl) * 9) << 8) + k0 + ty * 8;
#pragma unroll
            for (int dy = 0; dy < 3; ++dy) {
                int L = cl * 160 + dy * 40 + rbase;   // window cols xs-4..xs+11
                float4 q0 = *(const float4*)(&BsC[swz(L    ) * 4]);
                float4 q1 = *(const float4*)(&BsC[swz(L + 1) * 4]);
                float4 q2 = *(const float4*)(&BsC[swz(L + 2) * 4]);
                float4 q3 = *(const float4*)(&BsC[swz(L + 3) * 4]);
                float r[16] = {q0.x,q0.y,q0.z,q0.w, q1.x,q1.y,q1.z,q1.w,
                               q2.x,q2.y,q2.z,q2.w, q3.x,q3.y,q3.z,q3.w};
                const float* ap = wp + dy * 768;      // (dy*3)*256
#pragma unroll
                for (int dx = 0; dx < 3; ++dx) {
                    float4 a0 = *(const float4*)(ap + dx * 256);
                    float4 a1 = *(const float4*)(ap + dx * 256 + 4);
                    float a[8] = {a0.x,a0.y,a0.z,a0.w, a1.x,a1.y,a1.z,a1.w};
#pragma unroll
                    for (int ko = 0; ko < 8; ++ko)
#pragma unroll
                        for (int j = 0; j < 8; ++j)
                            acc[ko][j] = fmaf(a[ko], r[3 + j + dx], acc[ko][j]);
                }
            }
        }
        __syncthreads();
    }

    // ---- epilogue: bias + relu, float4 stores ----
    if (s < Pp) {
#pragma unroll
        for (int ko = 0; ko < 8; ++ko) {
            int k = k0 + ty * 8 + ko;
            float bias = b1[k];
            float4 v0, v1;
            v0.x = fmaxf(acc[ko][0] + bias, 0.f);
            v0.y = fmaxf(acc[ko][1] + bias, 0.f);
            v0.z = fmaxf(acc[ko][2] + bias, 0.f);
            v0.w = fmaxf(acc[ko][3] + bias, 0.f);
            v1.x = fmaxf(acc[ko][4] + bias, 0.f);
            v1.y = fmaxf(acc[ko][5] + bias, 0.f);
            v1.z = fmaxf(acc[ko][6] + bias, 0.f);
            v1.w = fmaxf(acc[ko][7] + bias, 0.f);
            float* dst = hid + ((size_t)n * Cc + k) * Pp + s;
            *(float4*)dst = v0;
            *(float4*)(dst + 4) = v1;
        }
    }
}

// ---------------------------------------------------------------------------
// Kernel 2: 1x1 conv to 81 logits + bias, softmax over 81, argmax over 80.
// Writes logits (output 2) and per-pixel (p = prob of argmax class, c) maps.
// ---------------------------------------------------------------------------
__global__ __launch_bounds__(256, 2)
void conv1x1_softmax(const float* __restrict__ hid, const float* __restrict__ w2,
                     const float* __restrict__ b2, float* __restrict__ logits,
                     float* __restrict__ pmap, int* __restrict__ cmap)
{
    __shared__ float w2s[64 * 84];   // [c_l][j], j padded 81->84 with zeros
    const int tid = threadIdx.x;
    const int p   = blockIdx.x * 256 + tid;
    const int n   = blockIdx.y;
    const bool valid = (p < Pp);
    const int psafe = valid ? p : 0;

    float acc[84];
#pragma unroll
    for (int j = 0; j < 84; ++j) acc[j] = 0.f;

#pragma unroll 1
    for (int c0 = 0; c0 < Cc; c0 += 64) {
        __syncthreads();
#pragma unroll
        for (int i = 0; i < 21; ++i) {   // 21*256 == 64*84
            int q  = i * 256 + tid;
            int cl = q / 84;
            int j  = q - cl * 84;
            float v = 0.f;
            if (j < NC1) v = w2[j * 256 + c0 + cl];
            w2s[cl * 84 + j] = v;
        }
        __syncthreads();

        const float* hptr = hid + ((size_t)n * Cc + c0) * Pp + psafe;
#pragma unroll 2
        for (int cl = 0; cl < 64; ++cl) {
            float h = hptr[(size_t)cl * Pp];
            const float4* wrow = (const float4*)(&w2s[cl * 84]);
#pragma unroll
            for (int f = 0; f < 21; ++f) {
                float4 wv = wrow[f];
                acc[f * 4 + 0] = fmaf(wv.x, h, acc[f * 4 + 0]);
                acc[f * 4 + 1] = fmaf(wv.y, h, acc[f * 4 + 1]);
                acc[f * 4 + 2] = fmaf(wv.z, h, acc[f * 4 + 2]);
                acc[f * 4 + 3] = fmaf(wv.w, h, acc[f * 4 + 3]);
            }
        }
    }

    if (valid) {
#pragma unroll
        for (int j = 0; j < NC1; ++j) acc[j] += b2[j];

        float* lp = logits + (size_t)n * NC1 * Pp + p;
#pragma unroll
        for (int j = 0; j < NC1; ++j) lp[(size_t)j * Pp] = acc[j];

        float m = -3.4e38f;
#pragma unroll
        for (int j = 0; j < NC1; ++j) m = fmaxf(m, acc[j]);
        float s = 0.f;
#pragma unroll
        for (int j = 0; j < NC1; ++j) s += __expf(acc[j] - m);
        float best = -3.4e38f; int bi = 0;
#pragma unroll
        for (int j = 0; j < NCLS; ++j) {   // first occurrence wins (strict >)
            if (acc[j] > best) { best = acc[j]; bi = j; }
        }
        pmap[n * Pp + p] = __expf(best - m) / s;
        cmap[n * Pp + p] = bi;
    }
}

// ---------------------------------------------------------------------------
// Kernel 3: score = p + 1{local max}. Only the argmax channel is nonzero at
// each pixel, so 81-ch local-max reduces to: no 8-neighbor with same class
// and strictly larger p (and p >= eps).
// ---------------------------------------------------------------------------
__global__ void local_score(const float* __restrict__ pmap, const int* __restrict__ cmap,
                            float* __restrict__ scores)
{
    int p = blockIdx.x * 256 + threadIdx.x;
    int n = blockIdx.y;
    if (p >= Pp) return;
    int base = n * Pp;
    float pv = pmap[base + p];
    int   c  = cmap[base + p];
    int y = p / Ww, xc = p - y * Ww;
    bool ok = (pv >= 1e-6f);
#pragma unroll
    for (int dy = -1; dy <= 1; ++dy)
#pragma unroll
        for (int dx = -1; dx <= 1; ++dx) {
            if (dy == 0 && dx == 0) continue;
            int yy = y + dy, xx = xc + dx;
            if (yy >= 0 && yy < Hh && xx >= 0 && xx < Ww) {
                int q = base + yy * Ww + xx;
                if (cmap[q] == c && pmap[q] > pv) ok = false;
            }
        }
    scores[base + p] = pv + (ok ? 1.f : 0.f);
}

// ---------------------------------------------------------------------------
// Kernel 4: per-batch top-100 (lax.top_k semantics: value desc, index asc on
// ties) via 100 iterations of block-wide max over LDS-resident scores, using
// composite key (float_bits << 32) | (0xFFFF - idx). Then gathers x / pos.
// ---------------------------------------------------------------------------
__global__ __launch_bounds__(256)
void topk_gather(const float* __restrict__ scores, const float* __restrict__ x,
                 const float* __restrict__ pos, float* __restrict__ oprop,
                 float* __restrict__ opos)
{
    __shared__ float sv[Pp];                 // 60.8 KB
    __shared__ int sidx[KTOP];
    __shared__ unsigned long long red[4];
    const int tid = threadIdx.x;
    const int n   = blockIdx.x;

    for (int i = tid; i < Pp; i += 256) sv[i] = scores[n * Pp + i];
    __syncthreads();

    for (int it = 0; it < KTOP; ++it) {
        unsigned long long best = 0ull;
        for (int i = tid; i < Pp; i += 256) {
            unsigned fb = __float_as_uint(sv[i]);   // scores > 0 => monotone bits
            unsigned long long key =
                ((unsigned long long)fb << 32) | (unsigned)(0xFFFF - i);
            best = key > best ? key : best;
        }
#pragma unroll
        for (int off = 32; off > 0; off >>= 1) {
            unsigned long long o = __shfl_down(best, off, 64);
            best = o > best ? o : best;
        }
        if ((tid & 63) == 0) red[tid >> 6] = best;
        __syncthreads();
        if (tid == 0) {
            unsigned long long b = red[0];
            b = red[1] > b ? red[1] : b;
            b = red[2] > b ? red[2] : b;
            b = red[3] > b ? red[3] : b;
            int idx = 0xFFFF - (int)(b & 0xFFFFFFFFull);
            sidx[it] = idx;
            sv[idx]  = 0.f;                  // remove winner
        }
        __syncthreads();
    }

    for (int t = tid; t < Cc * KTOP; t += 256) {
        int c = t / KTOP;
        int i = t - c * KTOP;
        int idx = sidx[i];
        oprop[n * Cc * KTOP + c * KTOP + i] = x[((size_t)n * Cc + c) * Pp + idx];
        opos [n * Cc * KTOP + c * KTOP + i] = pos[(size_t)c * Pp + idx];
    }
}

// ---------------------------------------------------------------------------
extern "C" void kernel_launch(void* const* d_in, const int* in_sizes, int n_in,
                              void* d_out, int out_size, void* d_ws, size_t ws_size,
                              hipStream_t stream)
{
    const float* x   = (const float*)d_in[0];
    const float* pos = (const float*)d_in[1];
    const float* w1  = (const float*)d_in[2];
    const float* b1  = (const float*)d_in[3];
    const float* w2  = (const float*)d_in[4];
    const float* b2  = (const float*)d_in[5];

    float* out    = (float*)d_out;
    float* oprop  = out;                                         // (8,256,100)
    float* oposE  = out + (size_t)NBATCH * Cc * KTOP;            // (8,256,100)
    float* logits = out + (size_t)2 * NBATCH * Cc * KTOP;        // (8,81,100,152)

    // w1t (2304x256 floats = 2.36 MB) borrows the logits region of d_out:
    // written before conv3x3, consumed by conv3x3, overwritten by conv1x1.
    float* w1t = logits;

    // workspace layout (floats): hid | pmap | cmap | scores
    float* ws     = (float*)d_ws;
    float* hid    = ws;                                          // 8*256*15200
    float* pmap   = ws + (size_t)NBATCH * Cc * Pp;               // 8*15200
    int*   cmap   = (int*)(pmap + (size_t)NBATCH * Pp);          // 8*15200
    float* scores = (float*)(cmap + (size_t)NBATCH * Pp);        // 8*15200

    transpose_w1<<<2304, 256, 0, stream>>>(w1, w1t);
    conv3x3_relu<<<dim3((Pp + BN - 1) / BN, Cc / BM, NBATCH), 256, 0, stream>>>(
        x, w1t, b1, hid);
    conv1x1_softmax<<<dim3((Pp + 255) / 256, NBATCH), 256, 0, stream>>>(
        hid, w2, b2, logits, pmap, cmap);
    local_score<<<dim3((Pp + 255) / 256, NBATCH), 256, 0, stream>>>(
        pmap, cmap, scores);
    topk_gather<<<NBATCH, 256, 0, stream>>>(scores, x, pos, oprop, oposE);
}

// Round 6
// 1722.700 us; speedup vs baseline: 3.6293x; 1.5126x over previous
//
#include <hip/hip_runtime.h>
#include <hip/hip_bf16.h>

// Problem constants
#define Hh    100
#define Ww    152
#define Pp    15200        // H*W
#define Cc    256
#define NBATCH 8
#define NC1   81
#define NCLS  80
#define KTOP  100

// padded x-tensor geometry (pixel-major bf16 hi/lo)
#define PROWS 102          // rows -1..100
#define PCOLS 154          // cols -1..152
#define PIXB  1024         // bytes per padded pixel: 256 hi + 256 lo bf16
#define XT_BATCH_BYTES ((size_t)PROWS * PCOLS * PIXB)   // 16,084,992

typedef __attribute__((ext_vector_type(8))) short  bf16x8;
typedef __attribute__((ext_vector_type(4))) float  f32x4;

__device__ __forceinline__ unsigned short bf16_bits(float v) {
    __hip_bfloat16 h = __float2bfloat16(v);
    return *(unsigned short*)&h;
}
__device__ __forceinline__ float bf16_back(float v) {
    __hip_bfloat16 h = __float2bfloat16(v);
    return __bfloat162float(h);
}

// ---------------------------------------------------------------------------
// Kernel 0a: pack w1 (OIHW fp32) into A-fragment order, bf16 hi/lo.
// Region r = ((s*9+t)*2+prec): 16 M-tiles x 64 lanes x 8 bf16 = 8192 shorts.
// Within region: mt=k>>4; lane=quad(c)*16 + (k&15); j=c&7.
// ---------------------------------------------------------------------------
__global__ void pack_w(const float* __restrict__ w1, unsigned short* __restrict__ wpk)
{
    int id = blockIdx.x * 256 + threadIdx.x;    // 0..65535
    int k = id >> 8, c = id & 255;
#pragma unroll
    for (int t = 0; t < 9; ++t) {
        float v = w1[(size_t)(k * 256 + c) * 9 + t];
        unsigned short hi = bf16_bits(v);
        unsigned short lo = bf16_bits(v - bf16_back(v));
        int region = ((c >> 5) * 9 + t) * 2;
        int base   = region * 8192;
        int pos    = (k >> 4) * 512 + ((c >> 3) & 3) * 128 + (k & 15) * 8 + (c & 7);
        wpk[base + pos]        = hi;
        wpk[base + 8192 + pos] = lo;
    }
}

// ---------------------------------------------------------------------------
// Kernel 0b: pack x into zero-padded pixel-major bf16 hi/lo:
// xT[n][row 0..101][col 0..153][256 hi | 256 lo]. Borders = 0 so conv taps
// need no bounds predicates at all.
// ---------------------------------------------------------------------------
__global__ void pack_x(const float* __restrict__ x, unsigned short* __restrict__ xT)
{
    int col = threadIdx.x;          // 0..255, active < PCOLS
    int row = blockIdx.x;           // 0..101
    int c   = blockIdx.y;           // 0..255
    int n   = blockIdx.z;
    if (col >= PCOLS) return;
    int yy = row - 1, xx = col - 1;
    float v = 0.f;
    if ((unsigned)yy < (unsigned)Hh && (unsigned)xx < (unsigned)Ww)
        v = x[((size_t)(n * Cc + c)) * Pp + yy * Ww + xx];
    unsigned short hi = bf16_bits(v);
    unsigned short lo = bf16_bits(v - bf16_back(v));
    size_t dst = (((size_t)n * PROWS + row) * PCOLS + col) * 512 + c;
    xT[dst]       = hi;
    xT[dst + 256] = lo;
}

// ---------------------------------------------------------------------------
// Kernel 1: 3x3 conv (SAME) + bias + ReLU via MFMA bf16x3 split.
// Block: 128 out-ch x 128 px, 4 waves, each a 64x64 tile = 4x4 mfma 16x16x32
// tiles. K-loop: 8 steps x 32 ch; taps unrolled (9); per (s,t): 16 frag loads
// (all direct global: A from wpk fragment-order, B from xTpad pixel-major)
// + 48 mfma (passes hh, hl, lh interleaved at distance 16).
// Layouts (m89/m120-verified): A[m=lane&15][c=quad*8+j],
// B[c=quad*8+j][n=lane&15], C/D col=lane&15, row=quad*4+reg.
// ---------------------------------------------------------------------------
__global__ __launch_bounds__(256)
void conv3x3_mfma(const unsigned short* __restrict__ xT,
                  const unsigned short* __restrict__ wpk,
                  const float* __restrict__ b1, float* __restrict__ hid)
{
    const int tid  = threadIdx.x;
    const int lane = tid & 63;
    const int wv   = tid >> 6;
    const int wm   = wv >> 1, wn = wv & 1;
    const int quad = lane >> 4, lq = lane & 15;
    const int p0 = blockIdx.x * 128;
    const int k0 = blockIdx.y * 128;
    const int n  = blockIdx.z;

    // per-lane B base pointers for the 4 N-tiles (clamped; tail discarded at store)
    const char* xb = (const char*)xT + (size_t)n * XT_BATCH_BYTES;
    const char* pb[4];
#pragma unroll
    for (int i = 0; i < 4; ++i) {
        int pix = p0 + wn * 64 + i * 16 + lq;
        pix = pix < Pp ? pix : Pp - 1;
        int y = pix / Ww;
        int xc = pix - y * Ww;
        pb[i] = xb + (size_t)((y + 1) * PCOLS + (xc + 1)) * PIXB + quad * 16;
    }

    f32x4 acc[4][4];
#pragma unroll
    for (int a = 0; a < 4; ++a)
#pragma unroll
        for (int b = 0; b < 4; ++b) acc[a][b] = 0;

    const char* wb = (const char*)wpk;
    // A byte offset of this wave's first M-tile: global M-tile = (k0>>4) + wm*4
    const int   alo = (k0 >> 4) * 1024 + (wm * 4) * 1024 + lane * 16;

#pragma unroll 1
    for (int s = 0; s < 8; ++s) {
#pragma unroll
        for (int t = 0; t < 9; ++t) {
            const int  dy = t / 3 - 1, dx = t % 3 - 1;
            const long toff = (long)(dy * PCOLS + dx) * PIXB;
            const char* ab = wb + (size_t)(s * 9 + t) * 32768 + alo;

            bf16x8 bh[4], bl[4], ah[4], al[4];
#pragma unroll
            for (int i = 0; i < 4; ++i) {
                const char* p = pb[i] + toff;
                bh[i] = *(const bf16x8*)(p);
                bl[i] = *(const bf16x8*)(p + 512);
            }
#pragma unroll
            for (int m = 0; m < 4; ++m) {
                const char* p = ab + m * 1024;
                ah[m] = *(const bf16x8*)(p);
                al[m] = *(const bf16x8*)(p + 16384);
            }
            // pass 1: hi*hi
#pragma unroll
            for (int m = 0; m < 4; ++m)
#pragma unroll
                for (int i = 0; i < 4; ++i)
                    acc[m][i] = __builtin_amdgcn_mfma_f32_16x16x32_bf16(ah[m], bh[i], acc[m][i], 0, 0, 0);
            // pass 2: hi*lo
#pragma unroll
            for (int m = 0; m < 4; ++m)
#pragma unroll
                for (int i = 0; i < 4; ++i)
                    acc[m][i] = __builtin_amdgcn_mfma_f32_16x16x32_bf16(ah[m], bl[i], acc[m][i], 0, 0, 0);
            // pass 3: lo*hi
#pragma unroll
            for (int m = 0; m < 4; ++m)
#pragma unroll
                for (int i = 0; i < 4; ++i)
                    acc[m][i] = __builtin_amdgcn_mfma_f32_16x16x32_bf16(al[m], bh[i], acc[m][i], 0, 0, 0);
        }
        // advance channel block: +32 ch * 2 B
#pragma unroll
        for (int i = 0; i < 4; ++i) pb[i] += 64;
    }

    // epilogue: bias + relu; D row = quad*4 + reg
#pragma unroll
    for (int m = 0; m < 4; ++m) {
        int kb = k0 + wm * 64 + m * 16 + quad * 4;
        float b0 = b1[kb], b1v = b1[kb + 1], b2v = b1[kb + 2], b3v = b1[kb + 3];
#pragma unroll
        for (int i = 0; i < 4; ++i) {
            int pix = p0 + wn * 64 + i * 16 + lq;
            if (pix < Pp) {
                float* hp = hid + ((size_t)n * Cc + kb) * Pp + pix;
                hp[0]           = fmaxf(acc[m][i].x + b0,  0.f);
                hp[Pp]          = fmaxf(acc[m][i].y + b1v, 0.f);
                hp[2 * Pp]      = fmaxf(acc[m][i].z + b2v, 0.f);
                hp[3 * (size_t)Pp] = fmaxf(acc[m][i].w + b3v, 0.f);
            }
        }
    }
}

// ---------------------------------------------------------------------------
// Kernel 2: 1x1 conv to 81 logits + bias, softmax over 81, argmax over 80.
// Writes logits (output 2) and per-pixel (p = prob of argmax class, c) maps.
// ---------------------------------------------------------------------------
__global__ __launch_bounds__(256, 2)
void conv1x1_softmax(const float* __restrict__ hid, const float* __restrict__ w2,
                     const float* __restrict__ b2, float* __restrict__ logits,
                     float* __restrict__ pmap, int* __restrict__ cmap)
{
    __shared__ float w2s[64 * 84];   // [c_l][j], j padded 81->84 with zeros
    const int tid = threadIdx.x;
    const int p   = blockIdx.x * 256 + tid;
    const int n   = blockIdx.y;
    const bool valid = (p < Pp);
    const int psafe = valid ? p : 0;

    float acc[84];
#pragma unroll
    for (int j = 0; j < 84; ++j) acc[j] = 0.f;

#pragma unroll 1
    for (int c0 = 0; c0 < Cc; c0 += 64) {
        __syncthreads();
#pragma unroll
        for (int i = 0; i < 21; ++i) {   // 21*256 == 64*84
            int q  = i * 256 + tid;
            int cl = q / 84;
            int j  = q - cl * 84;
            float v = 0.f;
            if (j < NC1) v = w2[j * 256 + c0 + cl];
            w2s[cl * 84 + j] = v;
        }
        __syncthreads();

        const float* hptr = hid + ((size_t)n * Cc + c0) * Pp + psafe;
#pragma unroll 2
        for (int cl = 0; cl < 64; ++cl) {
            float h = hptr[(size_t)cl * Pp];
            const float4* wrow = (const float4*)(&w2s[cl * 84]);
#pragma unroll
            for (int f = 0; f < 21; ++f) {
                float4 wv = wrow[f];
                acc[f * 4 + 0] = fmaf(wv.x, h, acc[f * 4 + 0]);
                acc[f * 4 + 1] = fmaf(wv.y, h, acc[f * 4 + 1]);
                acc[f * 4 + 2] = fmaf(wv.z, h, acc[f * 4 + 2]);
                acc[f * 4 + 3] = fmaf(wv.w, h, acc[f * 4 + 3]);
            }
        }
    }

    if (valid) {
#pragma unroll
        for (int j = 0; j < NC1; ++j) acc[j] += b2[j];

        float* lp = logits + (size_t)n * NC1 * Pp + p;
#pragma unroll
        for (int j = 0; j < NC1; ++j) lp[(size_t)j * Pp] = acc[j];

        float m = -3.4e38f;
#pragma unroll
        for (int j = 0; j < NC1; ++j) m = fmaxf(m, acc[j]);
        float s = 0.f;
#pragma unroll
        for (int j = 0; j < NC1; ++j) s += __expf(acc[j] - m);
        float best = -3.4e38f; int bi = 0;
#pragma unroll
        for (int j = 0; j < NCLS; ++j) {   // first occurrence wins (strict >)
            if (acc[j] > best) { best = acc[j]; bi = j; }
        }
        pmap[n * Pp + p] = __expf(best - m) / s;
        cmap[n * Pp + p] = bi;
    }
}

// ---------------------------------------------------------------------------
// Kernel 3: score = p + 1{local max}. Only the argmax channel is nonzero at
// each pixel, so 81-ch local-max reduces to: no 8-neighbor with same class
// and strictly larger p (and p >= eps).
// ---------------------------------------------------------------------------
__global__ void local_score(const float* __restrict__ pmap, const int* __restrict__ cmap,
                            float* __restrict__ scores)
{
    int p = blockIdx.x * 256 + threadIdx.x;
    int n = blockIdx.y;
    if (p >= Pp) return;
    int base = n * Pp;
    float pv = pmap[base + p];
    int   c  = cmap[base + p];
    int y = p / Ww, xc = p - y * Ww;
    bool ok = (pv >= 1e-6f);
#pragma unroll
    for (int dy = -1; dy <= 1; ++dy)
#pragma unroll
        for (int dx = -1; dx <= 1; ++dx) {
            if (dy == 0 && dx == 0) continue;
            int yy = y + dy, xx = xc + dx;
            if (yy >= 0 && yy < Hh && xx >= 0 && xx < Ww) {
                int q = base + yy * Ww + xx;
                if (cmap[q] == c && pmap[q] > pv) ok = false;
            }
        }
    scores[base + p] = pv + (ok ? 1.f : 0.f);
}

// ---------------------------------------------------------------------------
// Kernel 4: per-batch top-100 (lax.top_k semantics: value desc, index asc on
// ties) via 100 iterations of block-wide max over LDS-resident scores, using
// composite key (float_bits << 32) | (0xFFFF - idx). Then gathers x / pos.
// ---------------------------------------------------------------------------
__global__ __launch_bounds__(256)
void topk_gather(const float* __restrict__ scores, const float* __restrict__ x,
                 const float* __restrict__ pos, float* __restrict__ oprop,
                 float* __restrict__ opos)
{
    __shared__ float sv[Pp];                 // 60.8 KB
    __shared__ int sidx[KTOP];
    __shared__ unsigned long long red[4];
    const int tid = threadIdx.x;
    const int n   = blockIdx.x;

    for (int i = tid; i < Pp; i += 256) sv[i] = scores[n * Pp + i];
    __syncthreads();

    for (int it = 0; it < KTOP; ++it) {
        unsigned long long best = 0ull;
        for (int i = tid; i < Pp; i += 256) {
            unsigned fb = __float_as_uint(sv[i]);   // scores > 0 => monotone bits
            unsigned long long key =
                ((unsigned long long)fb << 32) | (unsigned)(0xFFFF - i);
            best = key > best ? key : best;
        }
#pragma unroll
        for (int off = 32; off > 0; off >>= 1) {
            unsigned long long o = __shfl_down(best, off, 64);
            best = o > best ? o : best;
        }
        if ((tid & 63) == 0) red[tid >> 6] = best;
        __syncthreads();
        if (tid == 0) {
            unsigned long long b = red[0];
            b = red[1] > b ? red[1] : b;
            b = red[2] > b ? red[2] : b;
            b = red[3] > b ? red[3] : b;
            int idx = 0xFFFF - (int)(b & 0xFFFFFFFFull);
            sidx[it] = idx;
            sv[idx]  = 0.f;                  // remove winner
        }
        __syncthreads();
    }

    for (int t = tid; t < Cc * KTOP; t += 256) {
        int c = t / KTOP;
        int i = t - c * KTOP;
        int idx = sidx[i];
        oprop[n * Cc * KTOP + c * KTOP + i] = x[((size_t)n * Cc + c) * Pp + idx];
        opos [n * Cc * KTOP + c * KTOP + i] = pos[(size_t)c * Pp + idx];
    }
}

// ---------------------------------------------------------------------------
extern "C" void kernel_launch(void* const* d_in, const int* in_sizes, int n_in,
                              void* d_out, int out_size, void* d_ws, size_t ws_size,
                              hipStream_t stream)
{
    const float* x   = (const float*)d_in[0];
    const float* pos = (const float*)d_in[1];
    const float* w1  = (const float*)d_in[2];
    const float* b1  = (const float*)d_in[3];
    const float* w2  = (const float*)d_in[4];
    const float* b2  = (const float*)d_in[5];

    float* out    = (float*)d_out;
    float* oprop  = out;                                         // (8,256,100)
    float* oposE  = out + (size_t)NBATCH * Cc * KTOP;            // (8,256,100)
    float* logits = out + (size_t)2 * NBATCH * Cc * KTOP;        // (8,81,100,152)

    // wpk (2.36 MB, bf16 fragment-ordered w1) borrows the logits region:
    // written by pack_w, consumed by conv3x3_mfma, overwritten by conv1x1.
    unsigned short* wpk = (unsigned short*)logits;

    // workspace: hid (124.5 MB) | xTpad (128.7 MB) | pmap | cmap | scores
    float* ws  = (float*)d_ws;
    float* hid = ws;                                             // 8*256*15200 f32
    unsigned short* xT = (unsigned short*)(ws + (size_t)NBATCH * Cc * Pp);
    char* after_xt = (char*)xT + (size_t)NBATCH * XT_BATCH_BYTES;
    float* pmap   = (float*)after_xt;                            // 8*15200
    int*   cmap   = (int*)(pmap + (size_t)NBATCH * Pp);          // 8*15200
    float* scores = (float*)(cmap + (size_t)NBATCH * Pp);        // 8*15200

    pack_w<<<256, 256, 0, stream>>>(w1, wpk);
    pack_x<<<dim3(PROWS, Cc, NBATCH), 256, 0, stream>>>(x, xT);
    conv3x3_mfma<<<dim3((Pp + 127) / 128, 2, NBATCH), 256, 0, stream>>>(
        xT, wpk, b1, hid);
    conv1x1_softmax<<<dim3((Pp + 255) / 256, NBATCH), 256, 0, stream>>>(
        hid, w2, b2, logits, pmap, cmap);
    local_score<<<dim3((Pp + 255) / 256, NBATCH), 256, 0, stream>>>(
        pmap, cmap, scores);
    topk_gather<<<NBATCH, 256, 0, stream>>>(scores, x, pos, oprop, oposE);
}